// Round 5
// baseline (465.729 us; speedup 1.0000x reference)
//
#include <hip/hip_runtime.h>

#define B_   32
#define C_   64
#define T_   300
#define J_   25
#define K9   9
constexpr int PLANE = T_ * J_;           // 7500
constexpr int BCTJ  = B_ * C_ * PLANE;   // 15,360,000
constexpr float BN_EPS = 1e-5f;
constexpr float BN_N   = (float)(B_ * T_ * J_);  // 240000

typedef __attribute__((ext_vector_type(8))) short bf16x8;
typedef __attribute__((ext_vector_type(4))) float f32x4;

__device__ inline unsigned short f2bf(float f) {
  unsigned u = __float_as_uint(f);
  unsigned r = (u + 0x7FFF + ((u >> 16) & 1)) >> 16;
  return (unsigned short)r;
}

// ---------------------------------------------------------------------------
// K0: weight prep.
//  tcn_w [o][c][kt] -> Wb[kt][o][c] bf16 ; gcn_w -> Gb[o][c] bf16 ;
//  AdT[n][m] = block-diag A^T (bf16, 256x256)
__global__ __launch_bounds__(256) void prep_kernel(const float* __restrict__ tw,
                                                   const float* __restrict__ gw,
                                                   const float* __restrict__ A,
                                                   unsigned short* __restrict__ Wb,
                                                   unsigned short* __restrict__ Gb,
                                                   unsigned short* __restrict__ AdT) {
  int idx = blockIdx.x * 256 + threadIdx.x;
  if (idx < C_ * C_ * K9) {
    int o = idx / (C_ * K9);
    int rem = idx % (C_ * K9);
    int c = rem / K9, kt = rem % K9;
    Wb[kt * (C_ * C_) + o * C_ + c] = f2bf(tw[idx]);
  } else if (idx < C_ * C_ * K9 + C_ * C_) {
    int i = idx - C_ * C_ * K9;
    Gb[i] = f2bf(gw[i]);
  } else if (idx < C_ * C_ * K9 + C_ * C_ + 256 * 256) {
    int i = idx - (C_ * C_ * K9 + C_ * C_);
    int n = i >> 8, m = i & 255;
    float v = 0.f;
    if (n < 250 && m < 250) {
      if (n / 25 == m / 25) v = A[(m % 25) * 25 + (n % 25)];
    }
    AdT[i] = f2bf(v);
  }
}

// ---------------------------------------------------------------------------
// K1: GCN via two chained MFMAs. Output layout TRANSPOSED: y1T[b][row][c].
constexpr int TTG = 10;
__global__ __launch_bounds__(256) void gcn_mfma_kernel(
    const float* __restrict__ x, const unsigned short* __restrict__ AdT,
    const unsigned short* __restrict__ Gb, const float* __restrict__ gbias,
    float* __restrict__ y1T) {
  __shared__ unsigned short Xs[C_ * 256];     // [c][m] swizzled, 32 KB
  __shared__ unsigned short XAs[256 * C_];    // [n][c] swizzled, 32 KB
  int bid = blockIdx.x;
  int b = bid / (T_ / TTG), tile = bid % (T_ / TTG);
  int t0 = tile * TTG;
  int tid = threadIdx.x;

  // ---- stage x tile as bf16 [c][m], XOR-swizzled, cols 250..255 zero ----
  const float* xsrc = x + (size_t)b * (C_ * PLANE) + (size_t)t0 * J_;
  for (int u = tid; u < C_ * 64; u += 256) {
    int c = u >> 6, qd = u & 63;
    int m = qd * 4;
    float4 v = {0.f, 0.f, 0.f, 0.f};
    if (m < 248) {
      v = *(const float4*)(xsrc + (size_t)c * PLANE + m);
    } else if (m == 248) {
      float2 t2 = *(const float2*)(xsrc + (size_t)c * PLANE + 248);
      v.x = t2.x; v.y = t2.y;
    }
    unsigned p0 = (unsigned)f2bf(v.x) | ((unsigned)f2bf(v.y) << 16);
    unsigned p1 = (unsigned)f2bf(v.z) | ((unsigned)f2bf(v.w) << 16);
    int elem = ((c << 8) | m) ^ ((c & 7) << 3);
    ((unsigned*)Xs)[elem >> 1] = p0;
    ((unsigned*)Xs)[(elem >> 1) + 1] = p1;
  }
  __syncthreads();

  int l = tid & 63, w = tid >> 6;
  int lr = l & 15, lh = l >> 4;
  int n0 = w * 64;

  // ---- pass 1: XA = X * Ad (block-diagonal => skip zero K-chunks) ----
  f32x4 acc1[4][4];
#pragma unroll
  for (int mf = 0; mf < 4; ++mf)
#pragma unroll
    for (int nf = 0; nf < 4; ++nf) acc1[mf][nf] = (f32x4)0.f;

  int qminw = ((n0 / 25) * 25) >> 5;
  int qmaxw = min(7, ((((n0 + 63) / 25) + 1) * 25 - 1) >> 5);
  for (int q = qminw; q <= qmaxw; ++q) {
    bf16x8 afx[4];
#pragma unroll
    for (int mf = 0; mf < 4; ++mf) {
      int c = mf * 16 + lr;
      int elem = ((c << 8) | (q * 32 + lh * 8)) ^ ((c & 7) << 3);
      afx[mf] = *(const bf16x8*)&Xs[elem];
    }
#pragma unroll
    for (int nf = 0; nf < 4; ++nf) {
      int nbase = n0 + nf * 16;
      int ql = ((nbase / 25) * 25) >> 5;
      int qh = min(7, ((((nbase + 15) / 25) + 1) * 25 - 1) >> 5);
      if (q < ql || q > qh) continue;
      int n = nbase + lr;
      bf16x8 bfx = *(const bf16x8*)&AdT[n * 256 + q * 32 + lh * 8];
#pragma unroll
      for (int mf = 0; mf < 4; ++mf)
        acc1[mf][nf] = __builtin_amdgcn_mfma_f32_16x16x32_bf16(afx[mf], bfx, acc1[mf][nf], 0, 0, 0);
    }
  }

  // ---- write XA to LDS [n][c] swizzled ----
#pragma unroll
  for (int mf = 0; mf < 4; ++mf) {
    int cb = mf * 16 + 4 * lh;
#pragma unroll
    for (int nf = 0; nf < 4; ++nf) {
      int n = n0 + nf * 16 + lr;
      unsigned p0 = (unsigned)f2bf(acc1[mf][nf][0]) | ((unsigned)f2bf(acc1[mf][nf][1]) << 16);
      unsigned p1 = (unsigned)f2bf(acc1[mf][nf][2]) | ((unsigned)f2bf(acc1[mf][nf][3]) << 16);
      int e0 = ((n << 6) | cb) ^ ((n & 7) << 3);
      ((unsigned*)XAs)[e0 >> 1] = p0;
      ((unsigned*)XAs)[(e0 >> 1) + 1] = p1;
    }
  }
  __syncthreads();

  // ---- pass 2: y1 = Gb * XA + bias ----
  f32x4 acc[4][4];
#pragma unroll
  for (int mf = 0; mf < 4; ++mf)
#pragma unroll
    for (int nf = 0; nf < 4; ++nf) acc[mf][nf] = (f32x4)0.f;

  bf16x8 af[4][2];
#pragma unroll
  for (int mf = 0; mf < 4; ++mf) {
    const unsigned short* wp = Gb + (mf * 16 + lr) * C_ + lh * 8;
    af[mf][0] = *(const bf16x8*)(wp);
    af[mf][1] = *(const bf16x8*)(wp + 32);
  }
  bf16x8 bfr[4][2];
#pragma unroll
  for (int nf = 0; nf < 4; ++nf) {
    int r = n0 + nf * 16 + lr;
    int sw = (r & 7) << 3;
    bfr[nf][0] = *(const bf16x8*)&XAs[((r << 6) | (lh * 8)) ^ sw];
    bfr[nf][1] = *(const bf16x8*)&XAs[((r << 6) | (32 + lh * 8)) ^ sw];
  }
#pragma unroll
  for (int mf = 0; mf < 4; ++mf)
#pragma unroll
    for (int nf = 0; nf < 4; ++nf) {
      acc[mf][nf] = __builtin_amdgcn_mfma_f32_16x16x32_bf16(af[mf][0], bfr[nf][0], acc[mf][nf], 0, 0, 0);
      acc[mf][nf] = __builtin_amdgcn_mfma_f32_16x16x32_bf16(af[mf][1], bfr[nf][1], acc[mf][nf], 0, 0, 0);
    }

  // ---- epilogue: float4 (4 consecutive o) to y1T[b][t0*25+n][c] ----
  float* ydst = y1T + ((size_t)b * PLANE + (size_t)t0 * J_) * C_;
#pragma unroll
  for (int mf = 0; mf < 4; ++mf) {
    float4 gb4 = *(const float4*)(gbias + mf * 16 + 4 * lh);
#pragma unroll
    for (int nf = 0; nf < 4; ++nf) {
      int n = n0 + nf * 16 + lr;
      if (n < 250) {
        float4 o4;
        o4.x = acc[mf][nf][0] + gb4.x;
        o4.y = acc[mf][nf][1] + gb4.y;
        o4.z = acc[mf][nf][2] + gb4.z;
        o4.w = acc[mf][nf][3] + gb4.w;
        *(float4*)(ydst + (size_t)n * C_ + mf * 16 + 4 * lh) = o4;
      }
    }
  }
}

// ---------------------------------------------------------------------------
// K2: BN1 stats on y1T -> partials (no atomics). grid = 32 b x 8 chunks.
constexpr int SCHUNK = 938;
__global__ __launch_bounds__(256) void stats1_kernel(const float* __restrict__ y1T,
                                                     float* __restrict__ part1) {
  int blk = blockIdx.x;
  int b = blk >> 3, ch = blk & 7;
  int r0 = ch * SCHUNK, r1 = min(PLANE, r0 + SCHUNK);
  int tid = threadIdx.x;
  int cq = (tid & 15) * 4, rg = tid >> 4;
  const float* base = y1T + (size_t)b * PLANE * C_;
  float4 s = {0,0,0,0}, q = {0,0,0,0};
  for (int r = r0 + rg; r < r1; r += 16) {
    float4 v = *(const float4*)(base + (size_t)r * C_ + cq);
    s.x += v.x; s.y += v.y; s.z += v.z; s.w += v.w;
    q.x += v.x*v.x; q.y += v.y*v.y; q.z += v.z*v.z; q.w += v.w*v.w;
  }
  __shared__ float red[2][16][64];
  red[0][rg][cq] = s.x; red[0][rg][cq+1] = s.y; red[0][rg][cq+2] = s.z; red[0][rg][cq+3] = s.w;
  red[1][rg][cq] = q.x; red[1][rg][cq+1] = q.y; red[1][rg][cq+2] = q.z; red[1][rg][cq+3] = q.w;
  __syncthreads();
  if (tid < 64) {
    float S = 0.f, Q = 0.f;
#pragma unroll
    for (int i = 0; i < 16; ++i) { S += red[0][i][tid]; Q += red[1][i][tid]; }
    part1[blk * 128 + tid] = S;
    part1[blk * 128 + 64 + tid] = Q;
  }
}

// ---------------------------------------------------------------------------
// K3: reduce partials -> BN params
__global__ void bnparam_reduce_kernel(const float* __restrict__ part, int nparts,
                                      const float* __restrict__ g,
                                      const float* __restrict__ b,
                                      float* __restrict__ bnp) {
  int c = threadIdx.x;
  if (c < C_) {
    float S = 0.f, Q = 0.f;
    for (int k = 0; k < nparts; ++k) {
      S += part[k * 128 + c];
      Q += part[k * 128 + 64 + c];
    }
    float mean = S / BN_N;
    float var = Q / BN_N - mean * mean;
    float inv = rsqrtf(var + BN_EPS);
    float sc = g[c] * inv;
    bnp[c] = sc;
    bnp[C_ + c] = b[c] - mean * sc;
  }
}

// ---------------------------------------------------------------------------
// K4: MFMA temporal conv from y1T; fused BN2 partial stats (no atomics).
constexpr int TT = 10;
constexpr int ZROWS_TOT = 456;           // 450 data + 6 zero pad
__global__ __launch_bounds__(256) void tcn_mfma_kernel(
    const float* __restrict__ y1T, const unsigned short* __restrict__ Wb,
    const float* __restrict__ bnp1, const float* __restrict__ tbias,
    float* __restrict__ y2, float* __restrict__ part2) {
  __shared__ unsigned short zs[ZROWS_TOT * C_];   // 58368 B
  __shared__ float sred[4][64], qred[4][64];      // 2 KB
  int bid = blockIdx.x;
  int b = bid / (T_ / TT), tile = bid % (T_ / TT);
  int t0 = tile * TT;
  int tid = threadIdx.x;

  // ---- stage z = relu(bn1(y1T)) bf16, swizzled [row][c]; conflict-free ----
  {
    int cq = (tid & 15) * 4, rg = tid >> 4;
    float4 sc4 = *(const float4*)(bnp1 + cq);
    float4 sh4 = *(const float4*)(bnp1 + C_ + cq);
    const float* base = y1T + (size_t)b * PLANE * C_;
    int g0 = t0 * J_ - 100;                       // global row of zs row 0
    for (int rr = rg; rr < 450; rr += 16) {
      int gr = g0 + rr;
      float4 z4 = {0.f, 0.f, 0.f, 0.f};
      if (gr >= 0 && gr < PLANE) {
        float4 v = *(const float4*)(base + (size_t)gr * C_ + cq);
        z4.x = fmaxf(fmaf(v.x, sc4.x, sh4.x), 0.f);
        z4.y = fmaxf(fmaf(v.y, sc4.y, sh4.y), 0.f);
        z4.z = fmaxf(fmaf(v.z, sc4.z, sh4.z), 0.f);
        z4.w = fmaxf(fmaf(v.w, sc4.w, sh4.w), 0.f);
      }
      unsigned p0 = (unsigned)f2bf(z4.x) | ((unsigned)f2bf(z4.y) << 16);
      unsigned p1 = (unsigned)f2bf(z4.z) | ((unsigned)f2bf(z4.w) << 16);
      int elem = ((rr << 6) | cq) ^ ((rr & 7) << 3);
      *(uint2*)&zs[elem] = make_uint2(p0, p1);
    }
    for (int u = tid; u < 6 * 16; u += 256) {
      int rr = 450 + (u >> 4), cc = (u & 15) * 4;
      int elem = ((rr << 6) | cc) ^ ((rr & 7) << 3);
      *(uint2*)&zs[elem] = make_uint2(0u, 0u);
    }
  }
  __syncthreads();

  int l = tid & 63, w = tid >> 6;
  int lr = l & 15, lh = l >> 4;
  int n0 = w * 64;
  f32x4 acc[4][4];
#pragma unroll
  for (int mf = 0; mf < 4; ++mf)
#pragma unroll
    for (int nf = 0; nf < 4; ++nf) acc[mf][nf] = (f32x4)0.f;

#pragma unroll
  for (int kt = 0; kt < K9; ++kt) {
    bf16x8 af[4][2];
#pragma unroll
    for (int mf = 0; mf < 4; ++mf) {
      const unsigned short* wp = Wb + kt * (C_ * C_) + (mf * 16 + lr) * C_ + lh * 8;
      af[mf][0] = *(const bf16x8*)(wp);
      af[mf][1] = *(const bf16x8*)(wp + 32);
    }
    bf16x8 bfr[4][2];
#pragma unroll
    for (int nf = 0; nf < 4; ++nf) {
      int r = n0 + nf * 16 + lr + 25 * kt;
      int sw = (r & 7) << 3;
      bfr[nf][0] = *(const bf16x8*)&zs[((r << 6) | (lh * 8)) ^ sw];
      bfr[nf][1] = *(const bf16x8*)&zs[((r << 6) | (32 + lh * 8)) ^ sw];
    }
#pragma unroll
    for (int mf = 0; mf < 4; ++mf)
#pragma unroll
      for (int nf = 0; nf < 4; ++nf) {
        acc[mf][nf] = __builtin_amdgcn_mfma_f32_16x16x32_bf16(af[mf][0], bfr[nf][0], acc[mf][nf], 0, 0, 0);
        acc[mf][nf] = __builtin_amdgcn_mfma_f32_16x16x32_bf16(af[mf][1], bfr[nf][1], acc[mf][nf], 0, 0, 0);
      }
  }

  // ---- epilogue: bias + store y2 [b][c][plane] + per-block BN2 partials ----
  float* ydst = y2 + (size_t)b * (C_ * PLANE) + (size_t)t0 * J_;
#pragma unroll
  for (int mf = 0; mf < 4; ++mf) {
    float4 tb4 = *(const float4*)(tbias + mf * 16 + 4 * lh);
#pragma unroll
    for (int reg = 0; reg < 4; ++reg) {
      int o = mf * 16 + 4 * lh + reg;
      float s = 0.f, q = 0.f;
#pragma unroll
      for (int nf = 0; nf < 4; ++nf) {
        int n = n0 + nf * 16 + lr;
        float v = acc[mf][nf][reg] + ((const float*)&tb4)[reg];
        if (n < 250) {
          ydst[(size_t)o * PLANE + n] = v;
          s += v; q += v * v;
        }
      }
#pragma unroll
      for (int m = 1; m < 16; m <<= 1) {
        s += __shfl_xor(s, m);
        q += __shfl_xor(q, m);
      }
      if (lr == 0) { sred[w][o] = s; qred[w][o] = q; }
    }
  }
  __syncthreads();
  if (tid < 64) {
    float S = sred[0][tid] + sred[1][tid] + sred[2][tid] + sred[3][tid];
    float Q = qred[0][tid] + qred[1][tid] + qred[2][tid] + qred[3][tid];
    part2[bid * 128 + tid] = S;
    part2[bid * 128 + 64 + tid] = Q;
  }
}

// ---------------------------------------------------------------------------
// K5: out = relu(bn2(y2) + x), in place on d_out
__global__ __launch_bounds__(256) void final_kernel(float* __restrict__ y2,
                                                    const float* __restrict__ x,
                                                    const float* __restrict__ bnp2) {
  int i = blockIdx.x * 256 + threadIdx.x;
  if (i >= BCTJ / 4) return;
  int c = (i / (PLANE / 4)) & (C_ - 1);
  float sc = bnp2[c], sh = bnp2[C_ + c];
  float4 v = ((const float4*)y2)[i];
  float4 xv = ((const float4*)x)[i];
  v.x = fmaxf(fmaf(v.x, sc, sh) + xv.x, 0.f);
  v.y = fmaxf(fmaf(v.y, sc, sh) + xv.y, 0.f);
  v.z = fmaxf(fmaf(v.z, sc, sh) + xv.z, 0.f);
  v.w = fmaxf(fmaf(v.w, sc, sh) + xv.w, 0.f);
  ((float4*)y2)[i] = v;
}

// ---------------------------------------------------------------------------
extern "C" void kernel_launch(void* const* d_in, const int* in_sizes, int n_in,
                              void* d_out, int out_size, void* d_ws, size_t ws_size,
                              hipStream_t stream) {
  const float* x     = (const float*)d_in[0];
  const float* A     = (const float*)d_in[1];
  const float* gcn_w = (const float*)d_in[2];
  const float* gcn_b = (const float*)d_in[3];
  const float* bn1_g = (const float*)d_in[4];
  const float* bn1_b = (const float*)d_in[5];
  const float* tcn_w = (const float*)d_in[6];
  const float* tcn_b = (const float*)d_in[7];
  const float* bn2_g = (const float*)d_in[8];
  const float* bn2_b = (const float*)d_in[9];
  float* out = (float*)d_out;

  float* y1T = (float*)d_ws;                              // 15,360,000 f32
  unsigned short* Wb  = (unsigned short*)(y1T + BCTJ);    // 36,864 bf16
  unsigned short* Gb  = Wb + C_ * C_ * K9;                // 4,096 bf16
  unsigned short* AdT = Gb + C_ * C_;                     // 65,536 bf16
  float* part1 = (float*)(AdT + 256 * 256);               // 256*128 f32
  float* part2 = part1 + 256 * 128;                       // 960*128 f32
  float* bnp   = part2 + 960 * 128;                       // 256 f32

  int prep_n = C_ * C_ * K9 + C_ * C_ + 256 * 256;
  prep_kernel<<<(prep_n + 255) / 256, 256, 0, stream>>>(tcn_w, gcn_w, A, Wb, Gb, AdT);
  gcn_mfma_kernel<<<B_ * (T_ / TTG), 256, 0, stream>>>(x, AdT, Gb, gcn_b, y1T);
  stats1_kernel<<<B_ * 8, 256, 0, stream>>>(y1T, part1);
  bnparam_reduce_kernel<<<1, 64, 0, stream>>>(part1, B_ * 8, bn1_g, bn1_b, bnp);
  tcn_mfma_kernel<<<B_ * (T_ / TT), 256, 0, stream>>>(y1T, Wb, bnp, tcn_b, out, part2);
  bnparam_reduce_kernel<<<1, 64, 0, stream>>>(part2, B_ * (T_ / TT), bn2_g, bn2_b, bnp + 128);
  final_kernel<<<BCTJ / 4 / 256, 256, 0, stream>>>(out, x, bnp + 128);
}

// Round 6
// 192.733 us; speedup vs baseline: 2.4164x; 2.4164x over previous
//
#include <hip/hip_runtime.h>

#define B_   32
#define C_   64
#define T_   300
#define J_   25
#define K9   9
constexpr int PLANE = T_ * J_;           // 7500
constexpr int BCTJ  = B_ * C_ * PLANE;   // 15,360,000
constexpr float BN_EPS = 1e-5f;
constexpr float BN_N   = (float)(B_ * T_ * J_);  // 240000

typedef __attribute__((ext_vector_type(8))) short bf16x8;
typedef __attribute__((ext_vector_type(4))) float f32x4;

__device__ inline unsigned short f2bf(float f) {
  unsigned u = __float_as_uint(f);
  unsigned r = (u + 0x7FFF + ((u >> 16) & 1)) >> 16;
  return (unsigned short)r;
}

// ---------------------------------------------------------------------------
// K0: weight prep.
__global__ __launch_bounds__(256) void prep_kernel(const float* __restrict__ tw,
                                                   const float* __restrict__ gw,
                                                   const float* __restrict__ A,
                                                   unsigned short* __restrict__ Wb,
                                                   unsigned short* __restrict__ Gb,
                                                   unsigned short* __restrict__ AdT) {
  int idx = blockIdx.x * 256 + threadIdx.x;
  if (idx < C_ * C_ * K9) {
    int o = idx / (C_ * K9);
    int rem = idx % (C_ * K9);
    int c = rem / K9, kt = rem % K9;
    Wb[kt * (C_ * C_) + o * C_ + c] = f2bf(tw[idx]);
  } else if (idx < C_ * C_ * K9 + C_ * C_) {
    int i = idx - C_ * C_ * K9;
    Gb[i] = f2bf(gw[i]);
  } else if (idx < C_ * C_ * K9 + C_ * C_ + 256 * 256) {
    int i = idx - (C_ * C_ * K9 + C_ * C_);
    int n = i >> 8, m = i & 255;
    float v = 0.f;
    if (n < 250 && m < 250) {
      if (n / 25 == m / 25) v = A[(m % 25) * 25 + (n % 25)];
    }
    AdT[i] = f2bf(v);
  }
}

// ---------------------------------------------------------------------------
// K1: GCN via two chained MFMAs. Output layout TRANSPOSED: y1T[b][row][c].
constexpr int TTG = 10;
__global__ __launch_bounds__(256) void gcn_mfma_kernel(
    const float* __restrict__ x, const unsigned short* __restrict__ AdT,
    const unsigned short* __restrict__ Gb, const float* __restrict__ gbias,
    float* __restrict__ y1T) {
  __shared__ unsigned short Xs[C_ * 256];     // [c][m] swizzled, 32 KB
  __shared__ unsigned short XAs[256 * C_];    // [n][c] swizzled, 32 KB
  int bid = blockIdx.x;
  int b = bid / (T_ / TTG), tile = bid % (T_ / TTG);
  int t0 = tile * TTG;
  int tid = threadIdx.x;

  const float* xsrc = x + (size_t)b * (C_ * PLANE) + (size_t)t0 * J_;
  for (int u = tid; u < C_ * 64; u += 256) {
    int c = u >> 6, qd = u & 63;
    int m = qd * 4;
    float4 v = {0.f, 0.f, 0.f, 0.f};
    if (m < 248) {
      v = *(const float4*)(xsrc + (size_t)c * PLANE + m);
    } else if (m == 248) {
      float2 t2 = *(const float2*)(xsrc + (size_t)c * PLANE + 248);
      v.x = t2.x; v.y = t2.y;
    }
    unsigned p0 = (unsigned)f2bf(v.x) | ((unsigned)f2bf(v.y) << 16);
    unsigned p1 = (unsigned)f2bf(v.z) | ((unsigned)f2bf(v.w) << 16);
    int elem = ((c << 8) | m) ^ ((c & 7) << 3);
    ((unsigned*)Xs)[elem >> 1] = p0;
    ((unsigned*)Xs)[(elem >> 1) + 1] = p1;
  }
  __syncthreads();

  int l = tid & 63, w = tid >> 6;
  int lr = l & 15, lh = l >> 4;
  int n0 = w * 64;

  // ---- pass 1: XA = X * Ad (block-diagonal => skip zero K-chunks) ----
  f32x4 acc1[4][4];
#pragma unroll
  for (int mf = 0; mf < 4; ++mf)
#pragma unroll
    for (int nf = 0; nf < 4; ++nf) acc1[mf][nf] = (f32x4)0.f;

  int qminw = ((n0 / 25) * 25) >> 5;
  int qmaxw = min(7, ((((n0 + 63) / 25) + 1) * 25 - 1) >> 5);
  for (int q = qminw; q <= qmaxw; ++q) {
    bf16x8 afx[4];
#pragma unroll
    for (int mf = 0; mf < 4; ++mf) {
      int c = mf * 16 + lr;
      int elem = ((c << 8) | (q * 32 + lh * 8)) ^ ((c & 7) << 3);
      afx[mf] = *(const bf16x8*)&Xs[elem];
    }
#pragma unroll
    for (int nf = 0; nf < 4; ++nf) {
      int nbase = n0 + nf * 16;
      int ql = ((nbase / 25) * 25) >> 5;
      int qh = min(7, ((((nbase + 15) / 25) + 1) * 25 - 1) >> 5);
      if (q < ql || q > qh) continue;
      int n = nbase + lr;
      bf16x8 bfx = *(const bf16x8*)&AdT[n * 256 + q * 32 + lh * 8];
#pragma unroll
      for (int mf = 0; mf < 4; ++mf)
        acc1[mf][nf] = __builtin_amdgcn_mfma_f32_16x16x32_bf16(afx[mf], bfx, acc1[mf][nf], 0, 0, 0);
    }
  }

  // ---- write XA to LDS [n][c] swizzled ----
#pragma unroll
  for (int mf = 0; mf < 4; ++mf) {
    int cb = mf * 16 + 4 * lh;
#pragma unroll
    for (int nf = 0; nf < 4; ++nf) {
      int n = n0 + nf * 16 + lr;
      unsigned p0 = (unsigned)f2bf(acc1[mf][nf][0]) | ((unsigned)f2bf(acc1[mf][nf][1]) << 16);
      unsigned p1 = (unsigned)f2bf(acc1[mf][nf][2]) | ((unsigned)f2bf(acc1[mf][nf][3]) << 16);
      int e0 = ((n << 6) | cb) ^ ((n & 7) << 3);
      ((unsigned*)XAs)[e0 >> 1] = p0;
      ((unsigned*)XAs)[(e0 >> 1) + 1] = p1;
    }
  }
  __syncthreads();

  // ---- pass 2: y1 = Gb * XA + bias ----
  f32x4 acc[4][4];
#pragma unroll
  for (int mf = 0; mf < 4; ++mf)
#pragma unroll
    for (int nf = 0; nf < 4; ++nf) acc[mf][nf] = (f32x4)0.f;

  bf16x8 af[4][2];
#pragma unroll
  for (int mf = 0; mf < 4; ++mf) {
    const unsigned short* wp = Gb + (mf * 16 + lr) * C_ + lh * 8;
    af[mf][0] = *(const bf16x8*)(wp);
    af[mf][1] = *(const bf16x8*)(wp + 32);
  }
  bf16x8 bfr[4][2];
#pragma unroll
  for (int nf = 0; nf < 4; ++nf) {
    int r = n0 + nf * 16 + lr;
    int sw = (r & 7) << 3;
    bfr[nf][0] = *(const bf16x8*)&XAs[((r << 6) | (lh * 8)) ^ sw];
    bfr[nf][1] = *(const bf16x8*)&XAs[((r << 6) | (32 + lh * 8)) ^ sw];
  }
#pragma unroll
  for (int mf = 0; mf < 4; ++mf)
#pragma unroll
    for (int nf = 0; nf < 4; ++nf) {
      acc[mf][nf] = __builtin_amdgcn_mfma_f32_16x16x32_bf16(af[mf][0], bfr[nf][0], acc[mf][nf], 0, 0, 0);
      acc[mf][nf] = __builtin_amdgcn_mfma_f32_16x16x32_bf16(af[mf][1], bfr[nf][1], acc[mf][nf], 0, 0, 0);
    }

  // ---- epilogue: float4 (4 consecutive o) to y1T[b][t0*25+n][c] ----
  float* ydst = y1T + ((size_t)b * PLANE + (size_t)t0 * J_) * C_;
#pragma unroll
  for (int mf = 0; mf < 4; ++mf) {
    float4 gb4 = *(const float4*)(gbias + mf * 16 + 4 * lh);
#pragma unroll
    for (int nf = 0; nf < 4; ++nf) {
      int n = n0 + nf * 16 + lr;
      if (n < 250) {
        float4 o4;
        o4.x = acc[mf][nf][0] + gb4.x;
        o4.y = acc[mf][nf][1] + gb4.y;
        o4.z = acc[mf][nf][2] + gb4.z;
        o4.w = acc[mf][nf][3] + gb4.w;
        *(float4*)(ydst + (size_t)n * C_ + mf * 16 + 4 * lh) = o4;
      }
    }
  }
}

// ---------------------------------------------------------------------------
// K2: BN1 stats on y1T -> partials (no atomics). grid = 32 b x 8 chunks.
constexpr int SCHUNK = 938;
__global__ __launch_bounds__(256) void stats1_kernel(const float* __restrict__ y1T,
                                                     float* __restrict__ part1) {
  int blk = blockIdx.x;
  int b = blk >> 3, ch = blk & 7;
  int r0 = ch * SCHUNK, r1 = min(PLANE, r0 + SCHUNK);
  int tid = threadIdx.x;
  int cq = (tid & 15) * 4, rg = tid >> 4;
  const float* base = y1T + (size_t)b * PLANE * C_;
  float4 s = {0,0,0,0}, q = {0,0,0,0};
  for (int r = r0 + rg; r < r1; r += 16) {
    float4 v = *(const float4*)(base + (size_t)r * C_ + cq);
    s.x += v.x; s.y += v.y; s.z += v.z; s.w += v.w;
    q.x += v.x*v.x; q.y += v.y*v.y; q.z += v.z*v.z; q.w += v.w*v.w;
  }
  __shared__ float red[2][16][64];
  red[0][rg][cq] = s.x; red[0][rg][cq+1] = s.y; red[0][rg][cq+2] = s.z; red[0][rg][cq+3] = s.w;
  red[1][rg][cq] = q.x; red[1][rg][cq+1] = q.y; red[1][rg][cq+2] = q.z; red[1][rg][cq+3] = q.w;
  __syncthreads();
  if (tid < 64) {
    float S = 0.f, Q = 0.f;
#pragma unroll
    for (int i = 0; i < 16; ++i) { S += red[0][i][tid]; Q += red[1][i][tid]; }
    part1[blk * 128 + tid] = S;
    part1[blk * 128 + 64 + tid] = Q;
  }
}

// ---------------------------------------------------------------------------
// K3: parallel reduce of partials -> BN params.  1024 thr = 16 grp x 64 c.
__global__ __launch_bounds__(1024) void bnparam_reduce_kernel(
    const float* __restrict__ part, int nparts,
    const float* __restrict__ g, const float* __restrict__ b,
    float* __restrict__ bnp) {
  int tid = threadIdx.x;
  int c = tid & 63, grp = tid >> 6;          // 16 groups
  float S = 0.f, Q = 0.f;
  for (int k = grp; k < nparts; k += 16) {
    S += part[k * 128 + c];
    Q += part[k * 128 + 64 + c];
  }
  __shared__ float sS[16][64], sQ[16][64];
  sS[grp][c] = S; sQ[grp][c] = Q;
  __syncthreads();
  if (tid < 64) {
    float St = 0.f, Qt = 0.f;
#pragma unroll
    for (int i = 0; i < 16; ++i) { St += sS[i][tid]; Qt += sQ[i][tid]; }
    float mean = St / BN_N;
    float var = Qt / BN_N - mean * mean;
    float inv = rsqrtf(var + BN_EPS);
    float sc = g[tid] * inv;
    bnp[tid] = sc;
    bnp[C_ + tid] = b[tid] - mean * sc;
  }
}

// ---------------------------------------------------------------------------
// K4: MFMA temporal conv from y1T; fused BN2 partial stats (no atomics).
constexpr int TT = 10;
constexpr int ZROWS_TOT = 456;
__global__ __launch_bounds__(256) void tcn_mfma_kernel(
    const float* __restrict__ y1T, const unsigned short* __restrict__ Wb,
    const float* __restrict__ bnp1, const float* __restrict__ tbias,
    float* __restrict__ y2, float* __restrict__ part2) {
  __shared__ unsigned short zs[ZROWS_TOT * C_];   // 58368 B
  __shared__ float sred[4][64], qred[4][64];      // 2 KB
  int bid = blockIdx.x;
  int b = bid / (T_ / TT), tile = bid % (T_ / TT);
  int t0 = tile * TT;
  int tid = threadIdx.x;

  {
    int cq = (tid & 15) * 4, rg = tid >> 4;
    float4 sc4 = *(const float4*)(bnp1 + cq);
    float4 sh4 = *(const float4*)(bnp1 + C_ + cq);
    const float* base = y1T + (size_t)b * PLANE * C_;
    int g0 = t0 * J_ - 100;
    for (int rr = rg; rr < 450; rr += 16) {
      int gr = g0 + rr;
      float4 z4 = {0.f, 0.f, 0.f, 0.f};
      if (gr >= 0 && gr < PLANE) {
        float4 v = *(const float4*)(base + (size_t)gr * C_ + cq);
        z4.x = fmaxf(fmaf(v.x, sc4.x, sh4.x), 0.f);
        z4.y = fmaxf(fmaf(v.y, sc4.y, sh4.y), 0.f);
        z4.z = fmaxf(fmaf(v.z, sc4.z, sh4.z), 0.f);
        z4.w = fmaxf(fmaf(v.w, sc4.w, sh4.w), 0.f);
      }
      unsigned p0 = (unsigned)f2bf(z4.x) | ((unsigned)f2bf(z4.y) << 16);
      unsigned p1 = (unsigned)f2bf(z4.z) | ((unsigned)f2bf(z4.w) << 16);
      int elem = ((rr << 6) | cq) ^ ((rr & 7) << 3);
      *(uint2*)&zs[elem] = make_uint2(p0, p1);
    }
    for (int u = tid; u < 6 * 16; u += 256) {
      int rr = 450 + (u >> 4), cc = (u & 15) * 4;
      int elem = ((rr << 6) | cc) ^ ((rr & 7) << 3);
      *(uint2*)&zs[elem] = make_uint2(0u, 0u);
    }
  }
  __syncthreads();

  int l = tid & 63, w = tid >> 6;
  int lr = l & 15, lh = l >> 4;
  int n0 = w * 64;
  f32x4 acc[4][4];
#pragma unroll
  for (int mf = 0; mf < 4; ++mf)
#pragma unroll
    for (int nf = 0; nf < 4; ++nf) acc[mf][nf] = (f32x4)0.f;

#pragma unroll
  for (int kt = 0; kt < K9; ++kt) {
    bf16x8 af[4][2];
#pragma unroll
    for (int mf = 0; mf < 4; ++mf) {
      const unsigned short* wp = Wb + kt * (C_ * C_) + (mf * 16 + lr) * C_ + lh * 8;
      af[mf][0] = *(const bf16x8*)(wp);
      af[mf][1] = *(const bf16x8*)(wp + 32);
    }
    bf16x8 bfr[4][2];
#pragma unroll
    for (int nf = 0; nf < 4; ++nf) {
      int r = n0 + nf * 16 + lr + 25 * kt;
      int sw = (r & 7) << 3;
      bfr[nf][0] = *(const bf16x8*)&zs[((r << 6) | (lh * 8)) ^ sw];
      bfr[nf][1] = *(const bf16x8*)&zs[((r << 6) | (32 + lh * 8)) ^ sw];
    }
#pragma unroll
    for (int mf = 0; mf < 4; ++mf)
#pragma unroll
      for (int nf = 0; nf < 4; ++nf) {
        acc[mf][nf] = __builtin_amdgcn_mfma_f32_16x16x32_bf16(af[mf][0], bfr[nf][0], acc[mf][nf], 0, 0, 0);
        acc[mf][nf] = __builtin_amdgcn_mfma_f32_16x16x32_bf16(af[mf][1], bfr[nf][1], acc[mf][nf], 0, 0, 0);
      }
  }

  float* ydst = y2 + (size_t)b * (C_ * PLANE) + (size_t)t0 * J_;
#pragma unroll
  for (int mf = 0; mf < 4; ++mf) {
    float4 tb4 = *(const float4*)(tbias + mf * 16 + 4 * lh);
#pragma unroll
    for (int reg = 0; reg < 4; ++reg) {
      int o = mf * 16 + 4 * lh + reg;
      float s = 0.f, q = 0.f;
#pragma unroll
      for (int nf = 0; nf < 4; ++nf) {
        int n = n0 + nf * 16 + lr;
        float v = acc[mf][nf][reg] + ((const float*)&tb4)[reg];
        if (n < 250) {
          ydst[(size_t)o * PLANE + n] = v;
          s += v; q += v * v;
        }
      }
#pragma unroll
      for (int m = 1; m < 16; m <<= 1) {
        s += __shfl_xor(s, m);
        q += __shfl_xor(q, m);
      }
      if (lr == 0) { sred[w][o] = s; qred[w][o] = q; }
    }
  }
  __syncthreads();
  if (tid < 64) {
    float S = sred[0][tid] + sred[1][tid] + sred[2][tid] + sred[3][tid];
    float Q = qred[0][tid] + qred[1][tid] + qred[2][tid] + qred[3][tid];
    part2[bid * 128 + tid] = S;
    part2[bid * 128 + 64 + tid] = Q;
  }
}

// ---------------------------------------------------------------------------
// K5: out = relu(bn2(y2) + x), in place on d_out
__global__ __launch_bounds__(256) void final_kernel(float* __restrict__ y2,
                                                    const float* __restrict__ x,
                                                    const float* __restrict__ bnp2) {
  int i = blockIdx.x * 256 + threadIdx.x;
  if (i >= BCTJ / 4) return;
  int c = (i / (PLANE / 4)) & (C_ - 1);
  float sc = bnp2[c], sh = bnp2[C_ + c];
  float4 v = ((const float4*)y2)[i];
  float4 xv = ((const float4*)x)[i];
  v.x = fmaxf(fmaf(v.x, sc, sh) + xv.x, 0.f);
  v.y = fmaxf(fmaf(v.y, sc, sh) + xv.y, 0.f);
  v.z = fmaxf(fmaf(v.z, sc, sh) + xv.z, 0.f);
  v.w = fmaxf(fmaf(v.w, sc, sh) + xv.w, 0.f);
  ((float4*)y2)[i] = v;
}

// ---------------------------------------------------------------------------
extern "C" void kernel_launch(void* const* d_in, const int* in_sizes, int n_in,
                              void* d_out, int out_size, void* d_ws, size_t ws_size,
                              hipStream_t stream) {
  const float* x     = (const float*)d_in[0];
  const float* A     = (const float*)d_in[1];
  const float* gcn_w = (const float*)d_in[2];
  const float* gcn_b = (const float*)d_in[3];
  const float* bn1_g = (const float*)d_in[4];
  const float* bn1_b = (const float*)d_in[5];
  const float* tcn_w = (const float*)d_in[6];
  const float* tcn_b = (const float*)d_in[7];
  const float* bn2_g = (const float*)d_in[8];
  const float* bn2_b = (const float*)d_in[9];
  float* out = (float*)d_out;

  float* y1T = (float*)d_ws;                              // 15,360,000 f32
  unsigned short* Wb  = (unsigned short*)(y1T + BCTJ);    // 36,864 bf16
  unsigned short* Gb  = Wb + C_ * C_ * K9;                // 4,096 bf16
  unsigned short* AdT = Gb + C_ * C_;                     // 65,536 bf16
  float* part1 = (float*)(AdT + 256 * 256);               // 256*128 f32
  float* part2 = part1 + 256 * 128;                       // 960*128 f32
  float* bnp   = part2 + 960 * 128;                       // 256 f32

  int prep_n = C_ * C_ * K9 + C_ * C_ + 256 * 256;
  prep_kernel<<<(prep_n + 255) / 256, 256, 0, stream>>>(tcn_w, gcn_w, A, Wb, Gb, AdT);
  gcn_mfma_kernel<<<B_ * (T_ / TTG), 256, 0, stream>>>(x, AdT, Gb, gcn_b, y1T);
  stats1_kernel<<<B_ * 8, 256, 0, stream>>>(y1T, part1);
  bnparam_reduce_kernel<<<1, 1024, 0, stream>>>(part1, B_ * 8, bn1_g, bn1_b, bnp);
  tcn_mfma_kernel<<<B_ * (T_ / TT), 256, 0, stream>>>(y1T, Wb, bnp, tcn_b, out, part2);
  bnparam_reduce_kernel<<<1, 1024, 0, stream>>>(part2, B_ * (T_ / TT), bn2_g, bn2_b, bnp + 128);
  final_kernel<<<BCTJ / 4 / 256, 256, 0, stream>>>(out, x, bnp + 128);
}